// Round 6
// baseline (273.854 us; speedup 1.0000x reference)
//
#include <hip/hip_runtime.h>

typedef unsigned short u16;
typedef float f32x4 __attribute__((ext_vector_type(4)));
typedef short s16x8 __attribute__((ext_vector_type(8)));
typedef short s16x4 __attribute__((ext_vector_type(4)));
typedef unsigned short u16x4 __attribute__((ext_vector_type(4)));

#define S_LEN 2048
#define HDIM 2048
#define NHEADS 16
#define HEAD_DIM 128

__device__ __forceinline__ u16 f2bf(float f) {
    unsigned u = __builtin_bit_cast(unsigned, f);
    u += 0x7FFFu + ((u >> 16) & 1u);
    return (u16)(u >> 16);
}

__device__ __forceinline__ void gload_lds16(const u16* g, u16* l) {
    __builtin_amdgcn_global_load_lds(
        (const __attribute__((address_space(1))) unsigned int*)(const void*)g,
        (__attribute__((address_space(3))) unsigned int*)(void*)l, 16, 0, 0);
}

// 16 hardware-transpose reads covering all 8 d-groups x 2 key-halves for one kk.
__device__ __forceinline__ void tr_read16(const u16* bptr, s16x4* o) {
    auto p = (const __attribute__((address_space(3))) u16*)(const void*)bptr;
    asm volatile(
        "ds_read_b64_tr_b16 %0, %16\n\t"
        "ds_read_b64_tr_b16 %1, %16 offset:1024\n\t"
        "ds_read_b64_tr_b16 %2, %16 offset:128\n\t"
        "ds_read_b64_tr_b16 %3, %16 offset:1152\n\t"
        "ds_read_b64_tr_b16 %4, %16 offset:256\n\t"
        "ds_read_b64_tr_b16 %5, %16 offset:1280\n\t"
        "ds_read_b64_tr_b16 %6, %16 offset:384\n\t"
        "ds_read_b64_tr_b16 %7, %16 offset:1408\n\t"
        "ds_read_b64_tr_b16 %8, %16 offset:512\n\t"
        "ds_read_b64_tr_b16 %9, %16 offset:1536\n\t"
        "ds_read_b64_tr_b16 %10, %16 offset:640\n\t"
        "ds_read_b64_tr_b16 %11, %16 offset:1664\n\t"
        "ds_read_b64_tr_b16 %12, %16 offset:768\n\t"
        "ds_read_b64_tr_b16 %13, %16 offset:1792\n\t"
        "ds_read_b64_tr_b16 %14, %16 offset:896\n\t"
        "ds_read_b64_tr_b16 %15, %16 offset:1920\n\t"
        "s_waitcnt lgkmcnt(0)"
        : "=&v"(o[0]), "=&v"(o[1]), "=&v"(o[2]), "=&v"(o[3]),
          "=&v"(o[4]), "=&v"(o[5]), "=&v"(o[6]), "=&v"(o[7]),
          "=&v"(o[8]), "=&v"(o[9]), "=&v"(o[10]), "=&v"(o[11]),
          "=&v"(o[12]), "=&v"(o[13]), "=&v"(o[14]), "=&v"(o[15])
        : "v"(p));
    __builtin_amdgcn_sched_barrier(0);
}

// ---------------- fp32 -> bf16 converts ----------------
__global__ void cvt_bf16(const float* __restrict__ in, u16* __restrict__ out, int n4, float scale) {
    int i = blockIdx.x * blockDim.x + threadIdx.x;
    int stride = gridDim.x * blockDim.x;
    for (; i < n4; i += stride) {
        float4 f = ((const float4*)in)[i];
        u16x4 r;
        r.x = f2bf(f.x * scale); r.y = f2bf(f.y * scale);
        r.z = f2bf(f.z * scale); r.w = f2bf(f.w * scale);
        *(u16x4*)(out + (size_t)i * 4) = r;
    }
}

__global__ void cvt_w4(const float* __restrict__ w0, const float* __restrict__ w1,
                       const float* __restrict__ w2, const float* __restrict__ w3,
                       u16* __restrict__ out, float scale0) {
    const int n4each = (HDIM * HDIM) / 4;
    int b = blockIdx.x;
    int which = b >> 11;
    const float* src = which == 0 ? w0 : which == 1 ? w1 : which == 2 ? w2 : w3;
    float sc = which == 0 ? scale0 : 1.0f;
    u16* dst = out + (size_t)which * (HDIM * HDIM);
    int i = (b & 2047) * 256 + threadIdx.x;
    const int stride = 2048 * 256;
    for (; i < n4each; i += stride) {
        float4 f = ((const float4*)src)[i];
        u16x4 r;
        r.x = f2bf(f.x * sc); r.y = f2bf(f.y * sc);
        r.z = f2bf(f.z * sc); r.w = f2bf(f.w * sc);
        *(u16x4*)(dst + (size_t)i * 4) = r;
    }
}

// ================= 8-phase 256x256 GEMM (QKV) =================
// C = A[M][K] * Bw[N][K]^T. BM=BN=256, BK=64. 512 thr = 8 waves (2M x 4N),
// wave tile 128x64. LDS 128 KB: 2 sides x (A 256x64 + B 256x64), XOR-swizzled
// 16B chunks. 8 phases / 2 K-tiles; counted vmcnt(4) at phases 4 & 8 only.
// Output col block selects C0/C1/C2 by (colB0>>11); row stride 2048 elems.
#define PBAR __builtin_amdgcn_s_barrier()
#define SGB0 __builtin_amdgcn_sched_barrier(0)
#define LGKM0 { asm volatile("s_waitcnt lgkmcnt(0)" ::: "memory"); SGB0; }

#define LDAF(AF, SAP, HALF)                                                        \
    _Pragma("unroll") for (int m_ = 0; m_ < 4; ++m_)                               \
    _Pragma("unroll") for (int k_ = 0; k_ < 2; ++k_)                               \
        AF[m_][k_] = *(const s16x8*)&SAP[(wm * 128 + (HALF) * 64 + m_ * 16 + rl) * 64 + chv[k_]];

#define LDBF(BF, SBP, BSET)                                                        \
    _Pragma("unroll") for (int n_ = 0; n_ < 4; ++n_) {                             \
        int nn_ = n_ >> 1, kk_ = n_ & 1;                                           \
        BF[nn_][kk_] = *(const s16x8*)&SBP[(wn * 64 + (BSET) * 32 + nn_ * 16 + rl) * 64 + chv[kk_]]; \
    }

#define MM16(AF, BF, QA, QB)                                                       \
    __builtin_amdgcn_s_setprio(1);                                                 \
    _Pragma("unroll") for (int m_ = 0; m_ < 4; ++m_)                               \
    _Pragma("unroll") for (int n_ = 0; n_ < 2; ++n_)                               \
    _Pragma("unroll") for (int k_ = 0; k_ < 2; ++k_)                               \
        acc[(QA) * 4 + m_][(QB) * 2 + n_] = __builtin_amdgcn_mfma_f32_16x16x32_bf16( \
            AF[m_][k_], BF[n_][k_], acc[(QA) * 4 + m_][(QB) * 2 + n_], 0, 0, 0);   \
    __builtin_amdgcn_s_setprio(0);

__global__ __launch_bounds__(512, 2) void gemm_8p(const u16* __restrict__ A, const u16* __restrict__ Bw,
                                                  void* __restrict__ C0, void* __restrict__ C1,
                                                  void* __restrict__ C2, int M, int N, int K) {
    __shared__ u16 lA[2][16384];   // [side][256 rows x 64], swizzled chunks
    __shared__ u16 lB[2][16384];

    int bid = blockIdx.x;
    const int nwg = gridDim.x;
    bid = (bid & 7) * (nwg >> 3) + (bid >> 3);   // bijective XCD swizzle (nwg%8==0)

    const int nbn = N >> 8;
    const int bm = bid / nbn, bn = bid % nbn;
    const int t = threadIdx.x, lane = t & 63, w = t >> 6;
    const int wm = w >> 2, wn = w & 3;           // 2M x 4N
    const int rqg = lane >> 4, rl = lane & 15;

    const size_t rowA0 = (size_t)bm * 256;
    const int colB0 = bn << 8;

    // staging bases: chunk c = t + i*512 covers one 128-row half (1024 chunks);
    // linear LDS dest, source chunk pre-swizzled: (c&7) ^ (row&7).
    const u16* srcA[2]; const u16* srcB[2]; int dofs[2];
#pragma unroll
    for (int i = 0; i < 2; ++i) {
        int c = t + i * 512;
        int row = c >> 3, ch = c & 7;
        srcA[i] = A + (rowA0 + row) * (size_t)K + ((ch ^ (row & 7)) << 3);
        srcB[i] = Bw + (size_t)(colB0 + row) * (size_t)K + ((ch ^ (row & 7)) << 3);
        dofs[i] = c * 8;
    }

    auto stA = [&](int side, int half, int tile) {
        const size_t go = (size_t)tile * 64 + (size_t)half * 128 * (size_t)K;
        u16* dst = &lA[side][half * 8192];
#pragma unroll
        for (int i = 0; i < 2; ++i) gload_lds16(srcA[i] + go, dst + dofs[i]);
    };
    auto stB = [&](int side, int half, int tile) {
        const size_t go = (size_t)tile * 64 + (size_t)half * 128 * (size_t)K;
        u16* dst = &lB[side][half * 8192];
#pragma unroll
        for (int i = 0; i < 2; ++i) gload_lds16(srcB[i] + go, dst + dofs[i]);
    };

    // fragment k-chunk offsets (elements), swizzle-corrected: row&7 == rl&7
    const int chv[2] = { ((0 * 4 + rqg) ^ (rl & 7)) << 3, ((1 * 4 + rqg) ^ (rl & 7)) << 3 };

    f32x4 acc[8][4] = {};
    s16x8 afA[4][2], afB[4][2], bf01[2][2], bf23[2][2];

    const int NT = K >> 6;        // 32
    const int NI = NT >> 1;       // 16

    // prologue: tiles 0 (side0) then 1 (side1); wait tile 0
    stB(0, 0, 0); stB(0, 1, 0); stA(0, 0, 0); stA(0, 1, 0);
    stB(1, 0, 1); stB(1, 1, 1); stA(1, 0, 1); stA(1, 1, 1);
    asm volatile("s_waitcnt vmcnt(8)" ::: "memory");
    PBAR;

    for (int i = 0; i < NI; ++i) {
        // ---------- side 0: tile 2i ----------
        {
            const u16* sAp = lA[0]; const u16* sBp = lB[0];
            // P1
            LDAF(afA, sAp, 0); LDBF(bf01, sBp, 0);
            if (i > 0) stA(1, 0, 2 * i + 1);
            PBAR; LGKM0;
            MM16(afA, bf01, 0, 0);
            PBAR;
            // P2
            LDBF(bf23, sBp, 1);
            if (i > 0) stA(1, 1, 2 * i + 1);
            PBAR; LGKM0;
            MM16(afA, bf23, 0, 1);
            PBAR;
            // P3
            LDAF(afB, sAp, 1);
            if (2 * i + 2 < NT) stB(0, 0, 2 * i + 2);
            PBAR; LGKM0;
            MM16(afB, bf01, 1, 0);
            PBAR;
            // P4 (no reads)
            if (2 * i + 2 < NT) stB(0, 1, 2 * i + 2);
            MM16(afB, bf23, 1, 1);
            if (2 * i + 2 < NT) { asm volatile("s_waitcnt vmcnt(4)" ::: "memory"); }
            else                { asm volatile("s_waitcnt vmcnt(0)" ::: "memory"); }
            PBAR;
        }
        // ---------- side 1: tile 2i+1 ----------
        {
            const u16* sAp = lA[1]; const u16* sBp = lB[1];
            // P5
            LDAF(afA, sAp, 0); LDBF(bf01, sBp, 0);
            if (2 * i + 2 < NT) stA(0, 0, 2 * i + 2);
            PBAR; LGKM0;
            MM16(afA, bf01, 0, 0);
            PBAR;
            // P6
            LDBF(bf23, sBp, 1);
            if (2 * i + 2 < NT) stA(0, 1, 2 * i + 2);
            PBAR; LGKM0;
            MM16(afA, bf23, 0, 1);
            PBAR;
            // P7
            LDAF(afB, sAp, 1);
            if (2 * i + 3 < NT) stB(1, 0, 2 * i + 3);
            PBAR; LGKM0;
            MM16(afB, bf01, 1, 0);
            PBAR;
            // P8 (no reads)
            if (2 * i + 3 < NT) stB(1, 1, 2 * i + 3);
            MM16(afB, bf23, 1, 1);
            if (2 * i + 3 < NT) { asm volatile("s_waitcnt vmcnt(4)" ::: "memory"); }
            else                { asm volatile("s_waitcnt vmcnt(0)" ::: "memory"); }
            PBAR;
        }
    }

    // epilogue: acc[q][n], row = wm*128 + q*16 + rqg*4 + j, col = wn*64 + n*16 + rl
    const int mat = colB0 >> 11;
    u16* Csel = (u16*)(mat == 0 ? C0 : mat == 1 ? C1 : C2);
    const int colb = (colB0 & 2047) + wn * 64;
#pragma unroll
    for (int q = 0; q < 8; ++q) {
#pragma unroll
        for (int n = 0; n < 4; ++n) {
#pragma unroll
            for (int j = 0; j < 4; ++j) {
                size_t row = rowA0 + wm * 128 + q * 16 + rqg * 4 + j;
                size_t col = colb + n * 16 + rl;
                Csel[row * 2048 + col] = f2bf(acc[q][n][j]);
            }
        }
    }
}

// ---------------- GEMM (Wo): m97-class BM=256 BN=128, counted 2-phase ----------------
template<int OUT_F32>
__global__ __launch_bounds__(512) void gemm256(const u16* __restrict__ A, const u16* __restrict__ Bw,
                                               void* __restrict__ C0, void* __restrict__ C1,
                                               void* __restrict__ C2, int M, int N, int K) {
    __shared__ u16 lA[2][256 * 64];
    __shared__ u16 lB[2][128 * 64];

    int bid = blockIdx.x;
    const int nwg = gridDim.x;
    bid = (bid & 7) * (nwg >> 3) + (bid >> 3);

    const int nbn = N >> 7;
    const int bm = bid / nbn, bn = bid % nbn;
    const int t = threadIdx.x, lane = t & 63, w = t >> 6;
    const int wm = w & 3, wn = w >> 2;
    const int rqg = lane >> 4, rl = lane & 15;

    const size_t rowA0 = (size_t)bm * 256;
    const int colB0 = bn << 7;

    const u16* srcA[4]; int dA[4];
#pragma unroll
    for (int i = 0; i < 4; ++i) {
        int c = t + i * 512;
        int row = c >> 3, ch = c & 7;
        srcA[i] = A + (rowA0 + row) * (size_t)K + ((ch ^ (row & 7)) << 3);
        dA[i] = c * 8;
    }
    const u16* srcB[2]; int dB[2];
#pragma unroll
    for (int i = 0; i < 2; ++i) {
        int c = t + i * 512;
        int row = c >> 3, ch = c & 7;
        srcB[i] = Bw + (size_t)(colB0 + row) * (size_t)K + ((ch ^ (row & 7)) << 3);
        dB[i] = c * 8;
    }

    auto stage = [&](int tile, int side) {
        const size_t go = (size_t)tile * 64;
#pragma unroll
        for (int i = 0; i < 4; ++i) gload_lds16(srcA[i] + go, &lA[side][dA[i]]);
#pragma unroll
        for (int i = 0; i < 2; ++i) gload_lds16(srcB[i] + go, &lB[side][dB[i]]);
    };

    const int chv[2] = { ((0 + rqg) ^ (rl & 7)) << 3, ((4 + rqg) ^ (rl & 7)) << 3 };
    const int arow = wm * 64;
    const int brow = wn * 64;

    f32x4 acc[4][4] = {};

    const int NT = K >> 6;
    stage(0, 0);
    stage(1, 1);

    for (int tt = 0; tt < NT; ++tt) {
        const int side = tt & 1;
        if (tt < NT - 1) asm volatile("s_waitcnt vmcnt(6)" ::: "memory");
        else             asm volatile("s_waitcnt vmcnt(0)" ::: "memory");
        __builtin_amdgcn_s_barrier();
        __builtin_amdgcn_sched_barrier(0);

        const u16* sA = lA[side];
        const u16* sB = lB[side];

        s16x8 af[4][2], bf01[2][2], bf23[2][2];
#pragma unroll
        for (int m = 0; m < 4; ++m)
#pragma unroll
            for (int kk = 0; kk < 2; ++kk)
                af[m][kk] = *(const s16x8*)&sA[(arow + m * 16 + rl) * 64 + chv[kk]];
#pragma unroll
        for (int n = 0; n < 2; ++n)
#pragma unroll
            for (int kk = 0; kk < 2; ++kk)
                bf01[n][kk] = *(const s16x8*)&sB[(brow + n * 16 + rl) * 64 + chv[kk]];

        __builtin_amdgcn_s_setprio(1);
#pragma unroll
        for (int m = 0; m < 4; ++m)
#pragma unroll
            for (int n = 0; n < 2; ++n)
#pragma unroll
                for (int kk = 0; kk < 2; ++kk)
                    acc[m][n] = __builtin_amdgcn_mfma_f32_16x16x32_bf16(af[m][kk], bf01[n][kk], acc[m][n], 0, 0, 0);
        __builtin_amdgcn_s_setprio(0);
        __builtin_amdgcn_s_barrier();

#pragma unroll
        for (int n = 0; n < 2; ++n)
#pragma unroll
            for (int kk = 0; kk < 2; ++kk)
                bf23[n][kk] = *(const s16x8*)&sB[(brow + (n + 2) * 16 + rl) * 64 + chv[kk]];
        asm volatile("s_waitcnt lgkmcnt(0)" ::: "memory");
        __builtin_amdgcn_sched_barrier(0);
        __builtin_amdgcn_s_barrier();
        __builtin_amdgcn_sched_barrier(0);
        if (tt + 2 < NT) stage(tt + 2, side);

        __builtin_amdgcn_s_setprio(1);
#pragma unroll
        for (int m = 0; m < 4; ++m)
#pragma unroll
            for (int n = 0; n < 2; ++n)
#pragma unroll
                for (int kk = 0; kk < 2; ++kk)
                    acc[m][n + 2] = __builtin_amdgcn_mfma_f32_16x16x32_bf16(af[m][kk], bf23[n][kk], acc[m][n + 2], 0, 0, 0);
        __builtin_amdgcn_s_setprio(0);
    }

    const int mat = colB0 >> 11;
    void* Csel = mat == 0 ? C0 : mat == 1 ? C1 : C2;
    const int colb = (colB0 & 2047) + wn * 64;
#pragma unroll
    for (int m = 0; m < 4; ++m) {
#pragma unroll
        for (int n = 0; n < 4; ++n) {
#pragma unroll
            for (int j = 0; j < 4; ++j) {
                size_t row = rowA0 + wm * 64 + m * 16 + rqg * 4 + j;
                size_t col = colb + n * 16 + rl;
                float v = acc[m][n][j];
                if (OUT_F32) ((float*)Csel)[row * 2048 + col] = v;
                else ((u16*)Csel)[row * 2048 + col] = f2bf(v);
            }
        }
    }
}

// ---------------- Flash attention (causal + ALiBi) ----------------
__global__ __launch_bounds__(512) void attn_kernel(const u16* __restrict__ Q, const u16* __restrict__ Kb,
                                                   const u16* __restrict__ Vb,
                                                   const float* __restrict__ alibi,
                                                   u16* __restrict__ O) {
    __shared__ u16 lK[2][64 * 128];
    __shared__ u16 lV[2][64 * 128];
    __shared__ u16 lP[8][16 * 80];

    const int bid = blockIdx.x;
    const int bh = bid & 31;
    const int p = bid >> 5;
    const int h = bh & 15, b = bh >> 4;
    const int t = threadIdx.x, lane = t & 63, w = t >> 6;
    const int rqg = lane >> 4, rl = lane & 15;

    const size_t bS = (size_t)b * S_LEN;
    const size_t hOff = (size_t)h * HEAD_DIM;

    const u16* ksrc[2]; const u16* vsrc[2]; int cdst[2];
#pragma unroll
    for (int i = 0; i < 2; ++i) {
        int c = t + i * 512;
        int krow = c >> 4, kch = c & 15;
        ksrc[i] = Kb + (bS + krow) * HDIM + hOff + ((kch ^ (krow & 7)) << 3);
        int vkey = ((c >> 6) << 2) + ((c >> 1) & 3);
        int vd = (((c >> 3) & 7) << 4) + ((c & 1) << 3);
        vsrc[i] = Vb + (bS + vkey) * HDIM + hOff + vd;
        cdst[i] = c * 8;
    }

    const float mslope2 = alibi[(size_t)h * S_LEN + 1] * 1.4426950408889634f;

    s16x8 ones;
#pragma unroll
    for (int i = 0; i < 8; ++i) ones[i] = (short)0x3F80;

    for (int sidx = 0; sidx < 2; ++sidx) {
        const int qt = sidx ? (15 - p) : p;
        const int q0w = qt * 128 + w * 16;

        const size_t baseQ = (bS + q0w + rl) * HDIM + hOff;
        s16x8 qf[4];
#pragma unroll
        for (int kk = 0; kk < 4; ++kk)
            qf[kk] = *(const s16x8*)(Q + baseQ + kk * 32 + rqg * 8);

        float m[4];
        f32x4 o[8]; f32x4 osum = {0.f, 0.f, 0.f, 0.f};
#pragma unroll
        for (int j = 0; j < 4; ++j) m[j] = -1e30f;
#pragma unroll
        for (int n = 0; n < 8; ++n) o[n] = (f32x4){0.f, 0.f, 0.f, 0.f};

        const int nkt = 2 * qt + 2;
        const int my_last = 2 * qt + (w >> 2);
        u16* lPw = lP[w];

#pragma unroll
        for (int i = 0; i < 2; ++i) {
            gload_lds16(ksrc[i], &lK[0][cdst[i]]);
            gload_lds16(vsrc[i], &lV[0][cdst[i]]);
        }
        __syncthreads();

        for (int kt = 0; kt < nkt; ++kt) {
            const int cur = kt & 1;
            if (kt + 1 < nkt) {
                const size_t goff = (size_t)(kt + 1) * 64 * HDIM;
#pragma unroll
                for (int i = 0; i < 2; ++i) {
                    gload_lds16(ksrc[i] + goff, &lK[cur ^ 1][cdst[i]]);
                    gload_lds16(vsrc[i] + goff, &lV[cur ^ 1][cdst[i]]);
                }
            }

            if (kt <= my_last) {
                const int k0 = kt * 64;

                f32x4 sfr[4] = {};
#pragma unroll
                for (int kk = 0; kk < 4; ++kk) {
#pragma unroll
                    for (int nt = 0; nt < 4; ++nt) {
                        int row = nt * 16 + rl;
                        int off = row * 256 + ((kk * 64 + rqg * 16) ^ ((row & 7) << 4));
                        s16x8 kf = *(const s16x8*)((const char*)lK[cur] + off);
                        sfr[nt] = __builtin_amdgcn_mfma_f32_16x16x32_bf16(qf[kk], kf, sfr[nt], 0, 0, 0);
                    }
                }

                const bool diag = (kt == my_last);
                float scv[4][4];
                float thr0 = m[0] + 8.f, thr1 = m[1] + 8.f, thr2 = m[2] + 8.f, thr3 = m[3] + 8.f;
                int small = 1;
#pragma unroll
                for (int nt = 0; nt < 4; ++nt) {
                    int key = k0 + nt * 16 + rl;
                    float al = mslope2 * (float)key;
#pragma unroll
                    for (int j = 0; j < 4; ++j) {
                        float v = sfr[nt][j] + al;
                        if (diag) {
                            int qrow = q0w + rqg * 4 + j;
                            v = (key <= qrow) ? v : -1e30f;
                        }
                        scv[nt][j] = v;
                        float thr = (j == 0) ? thr0 : (j == 1) ? thr1 : (j == 2) ? thr2 : thr3;
                        small &= (v <= thr) ? 1 : 0;
                    }
                }
                if (!__all(small)) {
                    float rmax[4];
#pragma unroll
                    for (int j = 0; j < 4; ++j)
                        rmax[j] = fmaxf(fmaxf(scv[0][j], scv[1][j]), fmaxf(scv[2][j], scv[3][j]));
#pragma unroll
                    for (int off = 1; off < 16; off <<= 1) {
#pragma unroll
                        for (int j = 0; j < 4; ++j) rmax[j] = fmaxf(rmax[j], __shfl_xor(rmax[j], off));
                    }
#pragma unroll
                    for (int j = 0; j < 4; ++j) {
                        float mn = fmaxf(m[j], rmax[j]);
                        float fac = exp2f(m[j] - mn);
                        m[j] = mn;
                        osum[j] *= fac;
#pragma unroll
                        for (int n = 0; n < 8; ++n) o[n][j] *= fac;
                    }
                }

#pragma unroll
                for (int nt = 0; nt < 4; ++nt) {
#pragma unroll
                    for (int j = 0; j < 4; ++j) {
                        float pv = exp2f(scv[nt][j] - m[j]);
                        lPw[(rqg * 4 + j) * 80 + nt * 16 + rl] = f2bf(pv);
                    }
                }

                const u16* lVbase = &lV[cur][0] + rqg * 1024 + rl * 4;
#pragma unroll
                for (int kk = 0; kk < 2; ++kk) {
                    s16x8 pf = *(const s16x8*)&lPw[rl * 80 + kk * 32 + rqg * 8];
                    osum = __builtin_amdgcn_mfma_f32_16x16x32_bf16(pf, ones, osum, 0, 0, 0);
                    s16x4 tr[16];
                    tr_read16(lVbase + kk * 4096, tr);
#pragma unroll
                    for (int n = 0; n < 8; ++n) {
                        s16x8 vf = __builtin_shufflevector(tr[2 * n], tr[2 * n + 1], 0, 1, 2, 3, 4, 5, 6, 7);
                        o[n] = __builtin_amdgcn_mfma_f32_16x16x32_bf16(pf, vf, o[n], 0, 0, 0);
                    }
                }
            }
            __syncthreads();
        }

        float inv[4];
#pragma unroll
        for (int j = 0; j < 4; ++j) inv[j] = 1.0f / osum[j];
#pragma unroll
        for (int n = 0; n < 8; ++n) {
#pragma unroll
            for (int j = 0; j < 4; ++j) {
                size_t row = bS + q0w + rqg * 4 + j;
                O[row * HDIM + hOff + n * 16 + rl] = f2bf(o[n][j] * inv[j]);
            }
        }
    }
}

extern "C" void kernel_launch(void* const* d_in, const int* in_sizes, int n_in,
                              void* d_out, int out_size, void* d_ws, size_t ws_size,
                              hipStream_t stream) {
    (void)in_sizes; (void)n_in; (void)out_size; (void)ws_size;
    const float* x     = (const float*)d_in[0];
    const float* alibi = (const float*)d_in[2];
    const float* Wq    = (const float*)d_in[3];
    const float* Wk    = (const float*)d_in[4];
    const float* Wv    = (const float*)d_in[5];
    const float* Wo    = (const float*)d_in[6];
    float* out = (float*)d_out;

    char* ws = (char*)d_ws;
    u16* xb  = (u16*)(ws + 0);
    u16* wqb = (u16*)(ws + 16777216);     // wq,wk,wv,wo contiguous
    u16* Qb  = (u16*)(ws + 50331648);
    u16* Kv  = Qb + 8388608;
    u16* Vv  = Kv + 8388608;
    u16* Ob  = Vv + 8388608;
    u16* wob = wqb + 3 * 4194304;

    const int M = 2 * S_LEN;   // 4096
    const int K = HDIM;        // 2048

    const float qscale = 0.08838834764831845f * 1.4426950408889634f;
    cvt_bf16<<<4096, 256, 0, stream>>>(x, xb, (2 * S_LEN * HDIM) / 4, 1.0f);
    cvt_w4<<<8192, 256, 0, stream>>>(Wq, Wk, Wv, Wo, wqb, qscale);

    // fused QKV projection: 8-phase 256x256, N=6144 -> 16x24 = 384 blocks
    gemm_8p<<<(M / 256) * (3 * HDIM / 256), 512, 0, stream>>>(xb, wqb, Qb, Kv, Vv, M, 3 * HDIM, K);

    attn_kernel<<<2 * NHEADS * 8, 512, 0, stream>>>(Qb, Kv, Vv, alibi, Ob);

    // output projection: BM=256 BN=128 -> 256 blocks (1/CU), fp32 out
    gemm256<1><<<(M / 256) * (HDIM / 128), 512, 0, stream>>>(Ob, wob, out, out, out, M, HDIM, K);
}

// Round 7
// 267.594 us; speedup vs baseline: 1.0234x; 1.0234x over previous
//
#include <hip/hip_runtime.h>

typedef unsigned short u16;
typedef float f32x4 __attribute__((ext_vector_type(4)));
typedef short s16x8 __attribute__((ext_vector_type(8)));
typedef short s16x4 __attribute__((ext_vector_type(4)));
typedef unsigned short u16x4 __attribute__((ext_vector_type(4)));

#define S_LEN 2048
#define HDIM 2048
#define NHEADS 16
#define HEAD_DIM 128

__device__ __forceinline__ u16 f2bf(float f) {
    unsigned u = __builtin_bit_cast(unsigned, f);
    u += 0x7FFFu + ((u >> 16) & 1u);
    return (u16)(u >> 16);
}

__device__ __forceinline__ void gload_lds16(const u16* g, u16* l) {
    __builtin_amdgcn_global_load_lds(
        (const __attribute__((address_space(1))) unsigned int*)(const void*)g,
        (__attribute__((address_space(3))) unsigned int*)(void*)l, 16, 0, 0);
}

// 16 hardware-transpose reads covering all 8 d-groups x 2 key-halves for one kk.
__device__ __forceinline__ void tr_read16(const u16* bptr, s16x4* o) {
    auto p = (const __attribute__((address_space(3))) u16*)(const void*)bptr;
    asm volatile(
        "ds_read_b64_tr_b16 %0, %16\n\t"
        "ds_read_b64_tr_b16 %1, %16 offset:1024\n\t"
        "ds_read_b64_tr_b16 %2, %16 offset:128\n\t"
        "ds_read_b64_tr_b16 %3, %16 offset:1152\n\t"
        "ds_read_b64_tr_b16 %4, %16 offset:256\n\t"
        "ds_read_b64_tr_b16 %5, %16 offset:1280\n\t"
        "ds_read_b64_tr_b16 %6, %16 offset:384\n\t"
        "ds_read_b64_tr_b16 %7, %16 offset:1408\n\t"
        "ds_read_b64_tr_b16 %8, %16 offset:512\n\t"
        "ds_read_b64_tr_b16 %9, %16 offset:1536\n\t"
        "ds_read_b64_tr_b16 %10, %16 offset:640\n\t"
        "ds_read_b64_tr_b16 %11, %16 offset:1664\n\t"
        "ds_read_b64_tr_b16 %12, %16 offset:768\n\t"
        "ds_read_b64_tr_b16 %13, %16 offset:1792\n\t"
        "ds_read_b64_tr_b16 %14, %16 offset:896\n\t"
        "ds_read_b64_tr_b16 %15, %16 offset:1920\n\t"
        "s_waitcnt lgkmcnt(0)"
        : "=&v"(o[0]), "=&v"(o[1]), "=&v"(o[2]), "=&v"(o[3]),
          "=&v"(o[4]), "=&v"(o[5]), "=&v"(o[6]), "=&v"(o[7]),
          "=&v"(o[8]), "=&v"(o[9]), "=&v"(o[10]), "=&v"(o[11]),
          "=&v"(o[12]), "=&v"(o[13]), "=&v"(o[14]), "=&v"(o[15])
        : "v"(p));
    __builtin_amdgcn_sched_barrier(0);
}

// ---------------- fp32 -> bf16 converts ----------------
__global__ void cvt_bf16(const float* __restrict__ in, u16* __restrict__ out, int n4, float scale) {
    int i = blockIdx.x * blockDim.x + threadIdx.x;
    int stride = gridDim.x * blockDim.x;
    for (; i < n4; i += stride) {
        float4 f = ((const float4*)in)[i];
        u16x4 r;
        r.x = f2bf(f.x * scale); r.y = f2bf(f.y * scale);
        r.z = f2bf(f.z * scale); r.w = f2bf(f.w * scale);
        *(u16x4*)(out + (size_t)i * 4) = r;
    }
}

__global__ void cvt_w4(const float* __restrict__ w0, const float* __restrict__ w1,
                       const float* __restrict__ w2, const float* __restrict__ w3,
                       u16* __restrict__ out, float scale0) {
    const int n4each = (HDIM * HDIM) / 4;
    int b = blockIdx.x;
    int which = b >> 11;
    const float* src = which == 0 ? w0 : which == 1 ? w1 : which == 2 ? w2 : w3;
    float sc = which == 0 ? scale0 : 1.0f;
    u16* dst = out + (size_t)which * (HDIM * HDIM);
    int i = (b & 2047) * 256 + threadIdx.x;
    const int stride = 2048 * 256;
    for (; i < n4each; i += stride) {
        float4 f = ((const float4*)src)[i];
        u16x4 r;
        r.x = f2bf(f.x * sc); r.y = f2bf(f.y * sc);
        r.z = f2bf(f.z * sc); r.w = f2bf(f.w * sc);
        *(u16x4*)(dst + (size_t)i * 4) = r;
    }
}

#define PBAR __builtin_amdgcn_s_barrier()
#define SGB0 __builtin_amdgcn_sched_barrier(0)
#define LGKM0 { asm volatile("s_waitcnt lgkmcnt(0)" ::: "memory"); SGB0; }

// ============ GEMM: C = A[M][K]*Bw[N][K]^T, BM=128 BN=256 BK=64, 8-phase-style ============
// 512 thr = 8 waves (2M x 4N), wave tile 64x64. LDS 96 KB (1 block/CU), XOR-swizzled
// 16B chunks. 4 phases / 2 K-tiles; counted vmcnt(2) at end of P2/P4 (never 0 mid-loop).
// Ledger: P1 stages B(2j+1), P2: A(2j+2), P3: B(2j+2), P4: A(2j+3); every restage is
// one full barrier after the buffer's last read; end-P2 drains A(2j+1)+B(2j+1),
// end-P4 drains A(2j+2)+B(2j+2).
// Grid must be a multiple of 8 (bijective XCD swizzle) and ideally k*256 (exact rounds).
template<int OUT_F32>
__global__ __launch_bounds__(512, 2) void gemm_128x256(const u16* __restrict__ A, const u16* __restrict__ Bw,
                                                       void* __restrict__ C0, void* __restrict__ C1,
                                                       void* __restrict__ C2, int M, int N, int K) {
    __shared__ u16 lA[2][128 * 64];   // 32 KB
    __shared__ u16 lB[2][256 * 64];   // 64 KB

    int bid = blockIdx.x;
    const int nwg = gridDim.x;
    bid = (bid & 7) * (nwg >> 3) + (bid >> 3);

    const int nbn = N >> 8;
    const int bm = bid / nbn, bn = bid % nbn;
    const int t = threadIdx.x, lane = t & 63, w = t >> 6;
    const int wm = w >> 2, wn = w & 3;          // 2M x 4N
    const int rqg = lane >> 4, rl = lane & 15;

    const size_t rowA0 = (size_t)bm * 128;
    const int colB0 = bn << 8;

    // staging: linear LDS dest chunk c, source chunk pre-swizzled (c&7)^(row&7)
    const u16* srcA[2]; int dA[2];
#pragma unroll
    for (int i = 0; i < 2; ++i) {
        int c = t + i * 512;
        int row = c >> 3, ch = c & 7;
        srcA[i] = A + (rowA0 + row) * (size_t)K + ((ch ^ (row & 7)) << 3);
        dA[i] = c * 8;
    }
    const u16* srcB[4]; int dB[4];
#pragma unroll
    for (int i = 0; i < 4; ++i) {
        int c = t + i * 512;
        int row = c >> 3, ch = c & 7;
        srcB[i] = Bw + (size_t)(colB0 + row) * (size_t)K + ((ch ^ (row & 7)) << 3);
        dB[i] = c * 8;
    }

    auto stA = [&](int side, int tile) {
        const size_t go = (size_t)tile * 64;
#pragma unroll
        for (int i = 0; i < 2; ++i) gload_lds16(srcA[i] + go, &lA[side][dA[i]]);
    };
    auto stB = [&](int side, int tile) {
        const size_t go = (size_t)tile * 64;
#pragma unroll
        for (int i = 0; i < 4; ++i) gload_lds16(srcB[i] + go, &lB[side][dB[i]]);
    };

    // fragment k-chunk offsets (elements), swizzle-corrected (row&7 == rl&7)
    const int chv[2] = { ((0 + rqg) ^ (rl & 7)) << 3, ((4 + rqg) ^ (rl & 7)) << 3 };
    const int arow = wm * 64, brow = wn * 64;

    f32x4 acc[4][4] = {};
    s16x8 af[4][2], bfL[2][2], bfH[2][2];

    auto ldA = [&](const u16* sAp) {
#pragma unroll
        for (int m = 0; m < 4; ++m)
#pragma unroll
            for (int k = 0; k < 2; ++k)
                af[m][k] = *(const s16x8*)&sAp[(arow + m * 16 + rl) * 64 + chv[k]];
    };
    auto ldB = [&](s16x8 (&bf)[2][2], const u16* sBp, int half) {
#pragma unroll
        for (int n = 0; n < 2; ++n)
#pragma unroll
            for (int k = 0; k < 2; ++k)
                bf[n][k] = *(const s16x8*)&sBp[(brow + half * 32 + n * 16 + rl) * 64 + chv[k]];
    };
    auto mm = [&](s16x8 (&bf)[2][2], int half) {
        __builtin_amdgcn_s_setprio(1);
#pragma unroll
        for (int m = 0; m < 4; ++m)
#pragma unroll
            for (int n = 0; n < 2; ++n)
#pragma unroll
                for (int k = 0; k < 2; ++k)
                    acc[m][half * 2 + n] = __builtin_amdgcn_mfma_f32_16x16x32_bf16(
                        af[m][k], bf[n][k], acc[m][half * 2 + n], 0, 0, 0);
        __builtin_amdgcn_s_setprio(0);
    };

    const int NT = K >> 6;     // 32
    const int NI = NT >> 1;    // 16

    // prologue: tiles 0 (side0), 1 (side1) = 12 loads; drain tile 0 (6 oldest)
    stA(0, 0); stB(0, 0); stA(1, 1); stB(1, 1);
    asm volatile("s_waitcnt vmcnt(6)" ::: "memory");
    PBAR;

    for (int j = 0; j < NI; ++j) {
        const bool more2 = (2 * j + 2 < NT);
        const bool more3 = (2 * j + 3 < NT);

        // ---- P1: tile 2j (side0), n-half L ----
        ldA(lA[0]); ldB(bfL, lB[0], 0);
        if (j > 0) stB(1, 2 * j + 1);           // lB[1] freed after prev P4
        PBAR; LGKM0;
        mm(bfL, 0);
        PBAR;
        // ---- P2: n-half H ----
        ldB(bfH, lB[0], 1);
        if (more2) stA(0, 2 * j + 2);           // lA[0] freed after P1
        PBAR; LGKM0;
        mm(bfH, 1);
        if (more2) { asm volatile("s_waitcnt vmcnt(2)" ::: "memory"); }  // drain A(2j+1),B(2j+1)
        else       { asm volatile("s_waitcnt vmcnt(0)" ::: "memory"); }
        PBAR;
        // ---- P3: tile 2j+1 (side1), n-half L ----
        ldA(lA[1]); ldB(bfL, lB[1], 0);
        if (more2) stB(0, 2 * j + 2);           // lB[0] freed after P2
        PBAR; LGKM0;
        mm(bfL, 0);
        PBAR;
        // ---- P4: n-half H ----
        ldB(bfH, lB[1], 1);
        if (more3) stA(1, 2 * j + 3);           // lA[1] freed after P3
        PBAR; LGKM0;
        mm(bfH, 1);
        if (more3) { asm volatile("s_waitcnt vmcnt(2)" ::: "memory"); }  // drain A(2j+2),B(2j+2)
        else       { asm volatile("s_waitcnt vmcnt(0)" ::: "memory"); }
        PBAR;
    }

    // epilogue: row = rowA0 + wm*64 + m*16 + rqg*4 + j, col = colb + n*16 + rl
    const int mat = colB0 >> 11;
    void* Csel = mat == 0 ? C0 : mat == 1 ? C1 : C2;
    const int colb = (colB0 & 2047) + wn * 64;
#pragma unroll
    for (int m = 0; m < 4; ++m) {
#pragma unroll
        for (int n = 0; n < 4; ++n) {
#pragma unroll
            for (int j = 0; j < 4; ++j) {
                size_t row = rowA0 + wm * 64 + m * 16 + rqg * 4 + j;
                size_t col = colb + n * 16 + rl;
                float v = acc[m][n][j];
                if (OUT_F32) ((float*)Csel)[row * 2048 + col] = v;
                else ((u16*)Csel)[row * 2048 + col] = f2bf(v);
            }
        }
    }
}

// ---------------- Flash attention (causal + ALiBi) ----------------
__global__ __launch_bounds__(512) void attn_kernel(const u16* __restrict__ Q, const u16* __restrict__ Kb,
                                                   const u16* __restrict__ Vb,
                                                   const float* __restrict__ alibi,
                                                   u16* __restrict__ O) {
    __shared__ u16 lK[2][64 * 128];
    __shared__ u16 lV[2][64 * 128];
    __shared__ u16 lP[8][16 * 80];

    const int bid = blockIdx.x;
    const int bh = bid & 31;
    const int p = bid >> 5;
    const int h = bh & 15, b = bh >> 4;
    const int t = threadIdx.x, lane = t & 63, w = t >> 6;
    const int rqg = lane >> 4, rl = lane & 15;

    const size_t bS = (size_t)b * S_LEN;
    const size_t hOff = (size_t)h * HEAD_DIM;

    const u16* ksrc[2]; const u16* vsrc[2]; int cdst[2];
#pragma unroll
    for (int i = 0; i < 2; ++i) {
        int c = t + i * 512;
        int krow = c >> 4, kch = c & 15;
        ksrc[i] = Kb + (bS + krow) * HDIM + hOff + ((kch ^ (krow & 7)) << 3);
        int vkey = ((c >> 6) << 2) + ((c >> 1) & 3);
        int vd = (((c >> 3) & 7) << 4) + ((c & 1) << 3);
        vsrc[i] = Vb + (bS + vkey) * HDIM + hOff + vd;
        cdst[i] = c * 8;
    }

    const float mslope2 = alibi[(size_t)h * S_LEN + 1] * 1.4426950408889634f;

    s16x8 ones;
#pragma unroll
    for (int i = 0; i < 8; ++i) ones[i] = (short)0x3F80;

    for (int sidx = 0; sidx < 2; ++sidx) {
        const int qt = sidx ? (15 - p) : p;
        const int q0w = qt * 128 + w * 16;

        const size_t baseQ = (bS + q0w + rl) * HDIM + hOff;
        s16x8 qf[4];
#pragma unroll
        for (int kk = 0; kk < 4; ++kk)
            qf[kk] = *(const s16x8*)(Q + baseQ + kk * 32 + rqg * 8);

        float m[4];
        f32x4 o[8]; f32x4 osum = {0.f, 0.f, 0.f, 0.f};
#pragma unroll
        for (int j = 0; j < 4; ++j) m[j] = -1e30f;
#pragma unroll
        for (int n = 0; n < 8; ++n) o[n] = (f32x4){0.f, 0.f, 0.f, 0.f};

        const int nkt = 2 * qt + 2;
        const int my_last = 2 * qt + (w >> 2);
        u16* lPw = lP[w];

#pragma unroll
        for (int i = 0; i < 2; ++i) {
            gload_lds16(ksrc[i], &lK[0][cdst[i]]);
            gload_lds16(vsrc[i], &lV[0][cdst[i]]);
        }
        __syncthreads();

        for (int kt = 0; kt < nkt; ++kt) {
            const int cur = kt & 1;
            if (kt + 1 < nkt) {
                const size_t goff = (size_t)(kt + 1) * 64 * HDIM;
#pragma unroll
                for (int i = 0; i < 2; ++i) {
                    gload_lds16(ksrc[i] + goff, &lK[cur ^ 1][cdst[i]]);
                    gload_lds16(vsrc[i] + goff, &lV[cur ^ 1][cdst[i]]);
                }
            }

            if (kt <= my_last) {
                const int k0 = kt * 64;

                f32x4 sfr[4] = {};
#pragma unroll
                for (int kk = 0; kk < 4; ++kk) {
#pragma unroll
                    for (int nt = 0; nt < 4; ++nt) {
                        int row = nt * 16 + rl;
                        int off = row * 256 + ((kk * 64 + rqg * 16) ^ ((row & 7) << 4));
                        s16x8 kf = *(const s16x8*)((const char*)lK[cur] + off);
                        sfr[nt] = __builtin_amdgcn_mfma_f32_16x16x32_bf16(qf[kk], kf, sfr[nt], 0, 0, 0);
                    }
                }

                const bool diag = (kt == my_last);
                float scv[4][4];
                float thr0 = m[0] + 8.f, thr1 = m[1] + 8.f, thr2 = m[2] + 8.f, thr3 = m[3] + 8.f;
                int small = 1;
#pragma unroll
                for (int nt = 0; nt < 4; ++nt) {
                    int key = k0 + nt * 16 + rl;
                    float al = mslope2 * (float)key;
#pragma unroll
                    for (int j = 0; j < 4; ++j) {
                        float v = sfr[nt][j] + al;
                        if (diag) {
                            int qrow = q0w + rqg * 4 + j;
                            v = (key <= qrow) ? v : -1e30f;
                        }
                        scv[nt][j] = v;
                        float thr = (j == 0) ? thr0 : (j == 1) ? thr1 : (j == 2) ? thr2 : thr3;
                        small &= (v <= thr) ? 1 : 0;
                    }
                }
                if (!__all(small)) {
                    float rmax[4];
#pragma unroll
                    for (int j = 0; j < 4; ++j)
                        rmax[j] = fmaxf(fmaxf(scv[0][j], scv[1][j]), fmaxf(scv[2][j], scv[3][j]));
#pragma unroll
                    for (int off = 1; off < 16; off <<= 1) {
#pragma unroll
                        for (int j = 0; j < 4; ++j) rmax[j] = fmaxf(rmax[j], __shfl_xor(rmax[j], off));
                    }
#pragma unroll
                    for (int j = 0; j < 4; ++j) {
                        float mn = fmaxf(m[j], rmax[j]);
                        float fac = exp2f(m[j] - mn);
                        m[j] = mn;
                        osum[j] *= fac;
#pragma unroll
                        for (int n = 0; n < 8; ++n) o[n][j] *= fac;
                    }
                }

#pragma unroll
                for (int nt = 0; nt < 4; ++nt) {
#pragma unroll
                    for (int j = 0; j < 4; ++j) {
                        float pv = exp2f(scv[nt][j] - m[j]);
                        lPw[(rqg * 4 + j) * 80 + nt * 16 + rl] = f2bf(pv);
                    }
                }

                const u16* lVbase = &lV[cur][0] + rqg * 1024 + rl * 4;
#pragma unroll
                for (int kk = 0; kk < 2; ++kk) {
                    s16x8 pf = *(const s16x8*)&lPw[rl * 80 + kk * 32 + rqg * 8];
                    osum = __builtin_amdgcn_mfma_f32_16x16x32_bf16(pf, ones, osum, 0, 0, 0);
                    s16x4 tr[16];
                    tr_read16(lVbase + kk * 4096, tr);
#pragma unroll
                    for (int n = 0; n < 8; ++n) {
                        s16x8 vf = __builtin_shufflevector(tr[2 * n], tr[2 * n + 1], 0, 1, 2, 3, 4, 5, 6, 7);
                        o[n] = __builtin_amdgcn_mfma_f32_16x16x32_bf16(pf, vf, o[n], 0, 0, 0);
                    }
                }
            }
            __syncthreads();
        }

        float inv[4];
#pragma unroll
        for (int j = 0; j < 4; ++j) inv[j] = 1.0f / osum[j];
#pragma unroll
        for (int n = 0; n < 8; ++n) {
#pragma unroll
            for (int j = 0; j < 4; ++j) {
                size_t row = bS + q0w + rqg * 4 + j;
                O[row * HDIM + hOff + n * 16 + rl] = f2bf(o[n][j] * inv[j]);
            }
        }
    }
}

extern "C" void kernel_launch(void* const* d_in, const int* in_sizes, int n_in,
                              void* d_out, int out_size, void* d_ws, size_t ws_size,
                              hipStream_t stream) {
    (void)in_sizes; (void)n_in; (void)out_size; (void)ws_size;
    const float* x     = (const float*)d_in[0];
    const float* alibi = (const float*)d_in[2];
    const float* Wq    = (const float*)d_in[3];
    const float* Wk    = (const float*)d_in[4];
    const float* Wv    = (const float*)d_in[5];
    const float* Wo    = (const float*)d_in[6];
    float* out = (float*)d_out;

    char* ws = (char*)d_ws;
    u16* xb  = (u16*)(ws + 0);
    u16* wqb = (u16*)(ws + 16777216);     // wq,wk,wv,wo contiguous
    u16* Qb  = (u16*)(ws + 50331648);
    u16* Kv  = Qb + 8388608;
    u16* Vv  = Kv + 8388608;
    u16* Ob  = Vv + 8388608;
    u16* wob = wqb + 3 * 4194304;

    const int M = 2 * S_LEN;   // 4096
    const int K = HDIM;        // 2048

    const float qscale = 0.08838834764831845f * 1.4426950408889634f;
    cvt_bf16<<<4096, 256, 0, stream>>>(x, xb, (2 * S_LEN * HDIM) / 4, 1.0f);
    cvt_w4<<<8192, 256, 0, stream>>>(Wq, Wk, Wv, Wo, wqb, qscale);

    // fused QKV projection: BM=128 BN=256 -> 32x24 = 768 blocks = 3 exact rounds
    gemm_128x256<0><<<(M / 128) * (3 * HDIM / 256), 512, 0, stream>>>(xb, wqb, Qb, Kv, Vv, M, 3 * HDIM, K);

    attn_kernel<<<2 * NHEADS * 8, 512, 0, stream>>>(Qb, Kv, Vv, alibi, Ob);

    // output projection: 32x8 = 256 blocks = 1 exact round, fp32 out
    gemm_128x256<1><<<(M / 128) * (HDIM / 256), 512, 0, stream>>>(Ob, wob, out, out, out, M, HDIM, K);
}

// Round 8
// 254.156 us; speedup vs baseline: 1.0775x; 1.0529x over previous
//
#include <hip/hip_runtime.h>

typedef unsigned short u16;
typedef float f32x4 __attribute__((ext_vector_type(4)));
typedef short s16x8 __attribute__((ext_vector_type(8)));
typedef short s16x4 __attribute__((ext_vector_type(4)));
typedef unsigned short u16x4 __attribute__((ext_vector_type(4)));

#define S_LEN 2048
#define HDIM 2048
#define NHEADS 16
#define HEAD_DIM 128

__device__ __forceinline__ u16 f2bf(float f) {
    unsigned u = __builtin_bit_cast(unsigned, f);
    u += 0x7FFFu + ((u >> 16) & 1u);
    return (u16)(u >> 16);
}

__device__ __forceinline__ void gload_lds16(const u16* g, u16* l) {
    __builtin_amdgcn_global_load_lds(
        (const __attribute__((address_space(1))) unsigned int*)(const void*)g,
        (__attribute__((address_space(3))) unsigned int*)(void*)l, 16, 0, 0);
}

#define PBAR __builtin_amdgcn_s_barrier()
#define SGB0 __builtin_amdgcn_sched_barrier(0)

// 16 hardware-transpose reads covering all 8 d-groups x 2 key-halves for one kk.
__device__ __forceinline__ void tr_read16(const u16* bptr, s16x4* o) {
    auto p = (const __attribute__((address_space(3))) u16*)(const void*)bptr;
    asm volatile(
        "ds_read_b64_tr_b16 %0, %16\n\t"
        "ds_read_b64_tr_b16 %1, %16 offset:1024\n\t"
        "ds_read_b64_tr_b16 %2, %16 offset:128\n\t"
        "ds_read_b64_tr_b16 %3, %16 offset:1152\n\t"
        "ds_read_b64_tr_b16 %4, %16 offset:256\n\t"
        "ds_read_b64_tr_b16 %5, %16 offset:1280\n\t"
        "ds_read_b64_tr_b16 %6, %16 offset:384\n\t"
        "ds_read_b64_tr_b16 %7, %16 offset:1408\n\t"
        "ds_read_b64_tr_b16 %8, %16 offset:512\n\t"
        "ds_read_b64_tr_b16 %9, %16 offset:1536\n\t"
        "ds_read_b64_tr_b16 %10, %16 offset:640\n\t"
        "ds_read_b64_tr_b16 %11, %16 offset:1664\n\t"
        "ds_read_b64_tr_b16 %12, %16 offset:768\n\t"
        "ds_read_b64_tr_b16 %13, %16 offset:1792\n\t"
        "ds_read_b64_tr_b16 %14, %16 offset:896\n\t"
        "ds_read_b64_tr_b16 %15, %16 offset:1920\n\t"
        "s_waitcnt lgkmcnt(0)"
        : "=&v"(o[0]), "=&v"(o[1]), "=&v"(o[2]), "=&v"(o[3]),
          "=&v"(o[4]), "=&v"(o[5]), "=&v"(o[6]), "=&v"(o[7]),
          "=&v"(o[8]), "=&v"(o[9]), "=&v"(o[10]), "=&v"(o[11]),
          "=&v"(o[12]), "=&v"(o[13]), "=&v"(o[14]), "=&v"(o[15])
        : "v"(p));
    __builtin_amdgcn_sched_barrier(0);
}

// ---------------- fp32 -> bf16 converts ----------------
__global__ void cvt_bf16(const float* __restrict__ in, u16* __restrict__ out, int n4, float scale) {
    int i = blockIdx.x * blockDim.x + threadIdx.x;
    int stride = gridDim.x * blockDim.x;
    for (; i < n4; i += stride) {
        float4 f = ((const float4*)in)[i];
        u16x4 r;
        r.x = f2bf(f.x * scale); r.y = f2bf(f.y * scale);
        r.z = f2bf(f.z * scale); r.w = f2bf(f.w * scale);
        *(u16x4*)(out + (size_t)i * 4) = r;
    }
}

__global__ void cvt_w4(const float* __restrict__ w0, const float* __restrict__ w1,
                       const float* __restrict__ w2, const float* __restrict__ w3,
                       u16* __restrict__ out, float scale0) {
    const int n4each = (HDIM * HDIM) / 4;
    int b = blockIdx.x;
    int which = b >> 11;
    const float* src = which == 0 ? w0 : which == 1 ? w1 : which == 2 ? w2 : w3;
    float sc = which == 0 ? scale0 : 1.0f;
    u16* dst = out + (size_t)which * (HDIM * HDIM);
    int i = (b & 2047) * 256 + threadIdx.x;
    const int stride = 2048 * 256;
    for (; i < n4each; i += stride) {
        float4 f = ((const float4*)src)[i];
        u16x4 r;
        r.x = f2bf(f.x * sc); r.y = f2bf(f.y * sc);
        r.z = f2bf(f.z * sc); r.w = f2bf(f.w * sc);
        *(u16x4*)(dst + (size_t)i * 4) = r;
    }
}

// ============ GEMM: C = A[M][K]*Bw[N][K]^T, BM=128 BN=256 BK=64 ============
// 3-buffer LDS ring (72 KB), ONE barrier + ONE 32-MFMA cluster per K-tile.
// Ledger: phase t reads side t%3, stages tile t+2 into side (t+2)%3 (last read
// at phase t-1, quiescent since that phase's end barrier). End of phase t:
// vmcnt(6) retires tile t+1's 6 loads; tile t+2's 6 stay in flight.
// XCD band map: xcd owns bm in [4*xcd, 4*xcd+4) (A band L2-resident), bn walked
// in groups of 8. Requires M==4096 (32 bm) and N a multiple of 2048 per C-select.
template<int OUT_F32>
__global__ __launch_bounds__(512, 2) void gemm_ring(const u16* __restrict__ A, const u16* __restrict__ Bw,
                                                    void* __restrict__ C0, void* __restrict__ C1,
                                                    void* __restrict__ C2, int M, int N, int K) {
    __shared__ u16 lds[3 * 24576];   // side: A [0,8192) + B [8192,24576)

    const int bid = blockIdx.x;
    const int xcd = bid & 7;
    const int q = bid >> 3;
    const int rr = q & 31, sc0 = q >> 5;
    const int bm = xcd * 4 + (rr & 3);
    const int bn = sc0 * 8 + (rr >> 2);

    const int t = threadIdx.x, lane = t & 63, w = t >> 6;
    const int wm = w >> 2, wn = w & 3;          // 2M x 4N, wave tile 64x64
    const int rqg = lane >> 4, rl = lane & 15;

    const size_t rowA0 = (size_t)bm * 128;
    const int colB0 = bn << 8;

    // staging: linear LDS dest chunk c, source chunk pre-swizzled (c&7)^(row&7)
    const u16* srcA[2]; int dA[2];
#pragma unroll
    for (int i = 0; i < 2; ++i) {
        int c = t + i * 512;
        int row = c >> 3, ch = c & 7;
        srcA[i] = A + (rowA0 + row) * (size_t)K + ((ch ^ (row & 7)) << 3);
        dA[i] = c * 8;
    }
    const u16* srcB[4]; int dB[4];
#pragma unroll
    for (int i = 0; i < 4; ++i) {
        int c = t + i * 512;
        int row = c >> 3, ch = c & 7;
        srcB[i] = Bw + (size_t)(colB0 + row) * (size_t)K + ((ch ^ (row & 7)) << 3);
        dB[i] = c * 8;
    }

    auto stage = [&](int tile, int s) {
        const size_t go = (size_t)tile * 64;
        u16* base = &lds[s * 24576];
#pragma unroll
        for (int i = 0; i < 2; ++i) gload_lds16(srcA[i] + go, base + dA[i]);
#pragma unroll
        for (int i = 0; i < 4; ++i) gload_lds16(srcB[i] + go, base + 8192 + dB[i]);
    };

    // fragment k-chunk offsets (elements), swizzle-corrected (row&7 == rl&7)
    const int chv[2] = { ((0 + rqg) ^ (rl & 7)) << 3, ((4 + rqg) ^ (rl & 7)) << 3 };
    const int arow = wm * 64, brow = wn * 64;

    f32x4 acc[4][4] = {};

    const int NT = K >> 6;     // 32

    stage(0, 0); stage(1, 1);
    asm volatile("s_waitcnt vmcnt(6)" ::: "memory");
    PBAR;

    int s = 0;
    for (int tt = 0; tt < NT; ++tt) {
        const u16* sA = &lds[s * 24576];
        const u16* sB = sA + 8192;

        // all fragments for this tile: 8 A + 8 B ds_read_b128
        s16x8 af[4][2], bf[4][2];
#pragma unroll
        for (int m = 0; m < 4; ++m)
#pragma unroll
            for (int k = 0; k < 2; ++k)
                af[m][k] = *(const s16x8*)&sA[(arow + m * 16 + rl) * 64 + chv[k]];
#pragma unroll
        for (int n = 0; n < 4; ++n)
#pragma unroll
            for (int k = 0; k < 2; ++k)
                bf[n][k] = *(const s16x8*)&sB[(brow + n * 16 + rl) * 64 + chv[k]];

        // stage tile tt+2 into the side last read at phase tt-1 (quiescent)
        int s2 = s + 2; if (s2 >= 3) s2 -= 3;
        if (tt + 2 < NT) stage(tt + 2, s2);
        SGB0;

        __builtin_amdgcn_s_setprio(1);
#pragma unroll
        for (int m = 0; m < 4; ++m)
#pragma unroll
            for (int n = 0; n < 4; ++n)
#pragma unroll
                for (int k = 0; k < 2; ++k)
                    acc[m][n] = __builtin_amdgcn_mfma_f32_16x16x32_bf16(af[m][k], bf[n][k], acc[m][n], 0, 0, 0);
        __builtin_amdgcn_s_setprio(0);

        if (tt + 2 < NT)      { asm volatile("s_waitcnt vmcnt(6)" ::: "memory"); }
        else if (tt + 1 < NT) { asm volatile("s_waitcnt vmcnt(0)" ::: "memory"); }
        PBAR;
        ++s; if (s == 3) s = 0;
    }

    // epilogue
    const int mat = colB0 >> 11;
    void* Csel = mat == 0 ? C0 : mat == 1 ? C1 : C2;
    const int colb = (colB0 & 2047) + wn * 64;
#pragma unroll
    for (int m = 0; m < 4; ++m) {
#pragma unroll
        for (int n = 0; n < 4; ++n) {
#pragma unroll
            for (int j = 0; j < 4; ++j) {
                size_t row = rowA0 + wm * 64 + m * 16 + rqg * 4 + j;
                size_t col = colb + n * 16 + rl;
                float v = acc[m][n][j];
                if (OUT_F32) ((float*)Csel)[row * 2048 + col] = v;
                else ((u16*)Csel)[row * 2048 + col] = f2bf(v);
            }
        }
    }
}

// ---------------- Flash attention (causal + ALiBi) ----------------
// Block = (b, h, pair p): strips qt=p and qt=15-p -> exactly 34 k-tile iters.
// 3-buffer K/V ring, depth-2 prefetch, counted vmcnt(4), ONE s_barrier per iter.
__global__ __launch_bounds__(512) void attn_kernel(const u16* __restrict__ Q, const u16* __restrict__ Kb,
                                                   const u16* __restrict__ Vb,
                                                   const float* __restrict__ alibi,
                                                   u16* __restrict__ O) {
    __shared__ u16 ldsKV[3 * 16384];   // side: K [0,8192) + V [8192,16384)
    __shared__ u16 lP[8][16 * 80];     // per-wave P [q][key], stride 80

    const int bid = blockIdx.x;
    const int bh = bid & 31;
    const int p = bid >> 5;
    const int h = bh & 15, b = bh >> 4;
    const int t = threadIdx.x, lane = t & 63, w = t >> 6;
    const int rqg = lane >> 4, rl = lane & 15;

    const size_t bS = (size_t)b * S_LEN;
    const size_t hOff = (size_t)h * HEAD_DIM;

    const u16* ksrc[2]; const u16* vsrc[2]; int cdst[2];
#pragma unroll
    for (int i = 0; i < 2; ++i) {
        int c = t + i * 512;
        int krow = c >> 4, kch = c & 15;
        ksrc[i] = Kb + (bS + krow) * HDIM + hOff + ((kch ^ (krow & 7)) << 3);
        int vkey = ((c >> 6) << 2) + ((c >> 1) & 3);
        int vd = (((c >> 3) & 7) << 4) + ((c & 1) << 3);
        vsrc[i] = Vb + (bS + vkey) * HDIM + hOff + vd;
        cdst[i] = c * 8;
    }

    auto stageKV = [&](int tile, int s) {
        const size_t goff = (size_t)tile * 64 * HDIM;
        u16* base = &ldsKV[s * 16384];
#pragma unroll
        for (int i = 0; i < 2; ++i) {
            gload_lds16(ksrc[i] + goff, base + cdst[i]);
            gload_lds16(vsrc[i] + goff, base + 8192 + cdst[i]);
        }
    };

    const float mslope2 = alibi[(size_t)h * S_LEN + 1] * 1.4426950408889634f;

    s16x8 ones;
#pragma unroll
    for (int i = 0; i < 8; ++i) ones[i] = (short)0x3F80;

    for (int sidx = 0; sidx < 2; ++sidx) {
        const int qt = sidx ? (15 - p) : p;
        const int q0w = qt * 128 + w * 16;

        const size_t baseQ = (bS + q0w + rl) * HDIM + hOff;
        s16x8 qf[4];
#pragma unroll
        for (int kk = 0; kk < 4; ++kk)
            qf[kk] = *(const s16x8*)(Q + baseQ + kk * 32 + rqg * 8);

        float m[4];
        f32x4 o[8]; f32x4 osum = {0.f, 0.f, 0.f, 0.f};
#pragma unroll
        for (int j = 0; j < 4; ++j) m[j] = -1e30f;
#pragma unroll
        for (int n = 0; n < 8; ++n) o[n] = (f32x4){0.f, 0.f, 0.f, 0.f};

        const int nkt = 2 * qt + 2;
        const int my_last = 2 * qt + (w >> 2);
        u16* lPw = lP[w];

        // prologue: tiles 0,1 into sides 0,1; wait tile 0 (4 oldest of 8)
        stageKV(0, 0); stageKV(1, 1);
        asm volatile("s_waitcnt vmcnt(4)" ::: "memory");
        PBAR;

        int s = 0;
        for (int kt = 0; kt < nkt; ++kt) {
            int s2 = s + 2; if (s2 >= 3) s2 -= 3;
            if (kt + 2 < nkt) stageKV(kt + 2, s2);

            if (kt <= my_last) {
                const int k0 = kt * 64;
                const u16* kbase = &ldsKV[s * 16384];

                f32x4 sfr[4] = {};
#pragma unroll
                for (int kk = 0; kk < 4; ++kk) {
#pragma unroll
                    for (int nt = 0; nt < 4; ++nt) {
                        int row = nt * 16 + rl;
                        int off = row * 256 + ((kk * 64 + rqg * 16) ^ ((row & 7) << 4));
                        s16x8 kf = *(const s16x8*)((const char*)kbase + off);
                        sfr[nt] = __builtin_amdgcn_mfma_f32_16x16x32_bf16(qf[kk], kf, sfr[nt], 0, 0, 0);
                    }
                }

                const bool diag = (kt == my_last);
                float scv[4][4];
                float thr0 = m[0] + 8.f, thr1 = m[1] + 8.f, thr2 = m[2] + 8.f, thr3 = m[3] + 8.f;
                int small = 1;
#pragma unroll
                for (int nt = 0; nt < 4; ++nt) {
                    int key = k0 + nt * 16 + rl;
                    float al = mslope2 * (float)key;
#pragma unroll
                    for (int j = 0; j < 4; ++j) {
                        float v = sfr[nt][j] + al;
                        if (diag) {
                            int qrow = q0w + rqg * 4 + j;
                            v = (key <= qrow) ? v : -1e30f;
                        }
                        scv[nt][j] = v;
                        float thr = (j == 0) ? thr0 : (j == 1) ? thr1 : (j == 2) ? thr2 : thr3;
                        small &= (v <= thr) ? 1 : 0;
                    }
                }
                if (!__all(small)) {
                    float rmax[4];
#pragma unroll
                    for (int j = 0; j < 4; ++j)
                        rmax[j] = fmaxf(fmaxf(scv[0][j], scv[1][j]), fmaxf(scv[2][j], scv[3][j]));
#pragma unroll
                    for (int off = 1; off < 16; off <<= 1) {
#pragma unroll
                        for (int j = 0; j < 4; ++j) rmax[j] = fmaxf(rmax[j], __shfl_xor(rmax[j], off));
                    }
#pragma unroll
                    for (int j = 0; j < 4; ++j) {
                        float mn = fmaxf(m[j], rmax[j]);
                        float fac = exp2f(m[j] - mn);
                        m[j] = mn;
                        osum[j] *= fac;
#pragma unroll
                        for (int n = 0; n < 8; ++n) o[n][j] *= fac;
                    }
                }

#pragma unroll
                for (int nt = 0; nt < 4; ++nt) {
#pragma unroll
                    for (int j = 0; j < 4; ++j) {
                        float pv = exp2f(scv[nt][j] - m[j]);
                        lPw[(rqg * 4 + j) * 80 + nt * 16 + rl] = f2bf(pv);
                    }
                }

                const u16* lVbase = &ldsKV[s * 16384] + 8192 + rqg * 1024 + rl * 4;
#pragma unroll
                for (int kk = 0; kk < 2; ++kk) {
                    s16x8 pf = *(const s16x8*)&lPw[rl * 80 + kk * 32 + rqg * 8];
                    osum = __builtin_amdgcn_mfma_f32_16x16x32_bf16(pf, ones, osum, 0, 0, 0);
                    s16x4 tr[16];
                    tr_read16(lVbase + kk * 4096, tr);
#pragma unroll
                    for (int n = 0; n < 8; ++n) {
                        s16x8 vf = __builtin_shufflevector(tr[2 * n], tr[2 * n + 1], 0, 1, 2, 3, 4, 5, 6, 7);
                        o[n] = __builtin_amdgcn_mfma_f32_16x16x32_bf16(pf, vf, o[n], 0, 0, 0);
                    }
                }
            }

            if (kt + 2 < nkt)      { asm volatile("s_waitcnt vmcnt(4)" ::: "memory"); }
            else if (kt + 1 < nkt) { asm volatile("s_waitcnt vmcnt(0)" ::: "memory"); }
            PBAR;
            ++s; if (s == 3) s = 0;
        }

        float inv[4];
#pragma unroll
        for (int j = 0; j < 4; ++j) inv[j] = 1.0f / osum[j];
#pragma unroll
        for (int n = 0; n < 8; ++n) {
#pragma unroll
            for (int j = 0; j < 4; ++j) {
                size_t row = bS + q0w + rqg * 4 + j;
                O[row * HDIM + hOff + n * 16 + rl] = f2bf(o[n][j] * inv[j]);
            }
        }
    }
}

extern "C" void kernel_launch(void* const* d_in, const int* in_sizes, int n_in,
                              void* d_out, int out_size, void* d_ws, size_t ws_size,
                              hipStream_t stream) {
    (void)in_sizes; (void)n_in; (void)out_size; (void)ws_size;
    const float* x     = (const float*)d_in[0];
    const float* alibi = (const float*)d_in[2];
    const float* Wq    = (const float*)d_in[3];
    const float* Wk    = (const float*)d_in[4];
    const float* Wv    = (const float*)d_in[5];
    const float* Wo    = (const float*)d_in[6];
    float* out = (float*)d_out;

    char* ws = (char*)d_ws;
    u16* xb  = (u16*)(ws + 0);
    u16* wqb = (u16*)(ws + 16777216);     // wq,wk,wv,wo contiguous
    u16* Qb  = (u16*)(ws + 50331648);
    u16* Kv  = Qb + 8388608;
    u16* Vv  = Kv + 8388608;
    u16* Ob  = Vv + 8388608;
    u16* wob = wqb + 3 * 4194304;

    const int M = 2 * S_LEN;   // 4096
    const int K = HDIM;        // 2048

    const float qscale = 0.08838834764831845f * 1.4426950408889634f;
    cvt_bf16<<<4096, 256, 0, stream>>>(x, xb, (2 * S_LEN * HDIM) / 4, 1.0f);
    cvt_w4<<<8192, 256, 0, stream>>>(Wq, Wk, Wv, Wo, wqb, qscale);

    // fused QKV projection: 32 bm x 24 bn = 768 blocks = 3 exact rounds
    gemm_ring<0><<<(M / 128) * (3 * HDIM / 256), 512, 0, stream>>>(xb, wqb, Qb, Kv, Vv, M, 3 * HDIM, K);

    attn_kernel<<<2 * NHEADS * 8, 512, 0, stream>>>(Qb, Kv, Vv, alibi, Ob);

    // output projection: 32 bm x 8 bn = 256 blocks = 1 exact round, fp32 out
    gemm_ring<1><<<(M / 128) * (HDIM / 256), 512, 0, stream>>>(Ob, wob, out, out, out, M, HDIM, K);
}